// Round 21
// baseline (322.462 us; speedup 1.0000x reference)
//
#include <hip/hip_runtime.h>
#include <hip/hip_bf16.h>

#define NEG 0.2f
#define FNEG_MAX -3.402823466e38f

// round-to-nearest-even fp32 -> bf16 (as u16)
__device__ __forceinline__ unsigned short f2bf(float f){
  unsigned u = __float_as_uint(f);
  return (unsigned short)((u + 0x7fffu + ((u >> 16) & 1u)) >> 16);
}
__device__ __forceinline__ float bflo(unsigned u){ return __uint_as_float(u << 16); }
__device__ __forceinline__ float bfhi(unsigned u){ return __uint_as_float(u & 0xffff0000u); }

// ============ CSR build: degree count + per-edge position (atomic ret) ======
__global__ __launch_bounds__(256)
void k_count(const int* __restrict__ dst, int* __restrict__ deg,
             int* __restrict__ pos, int ne){
  int e = blockIdx.x*256 + threadIdx.x;
  if (e < ne) pos[e] = atomicAdd(&deg[dst[e]], 1);
}

#define SCB 512
__global__ __launch_bounds__(SCB)
void k_scan1(const int* __restrict__ deg, int* __restrict__ off,
             int* __restrict__ bsum, int n){
  __shared__ int lds[SCB];
  int t = threadIdx.x, i = blockIdx.x*SCB + t;
  int x = (i < n) ? deg[i] : 0;
  lds[t] = x; __syncthreads();
  for (int s = 1; s < SCB; s <<= 1){
    int v = (t >= s) ? lds[t-s] : 0;
    __syncthreads();
    lds[t] += v;
    __syncthreads();
  }
  if (i < n) off[i] = lds[t] - x;            // exclusive
  if (t == SCB-1) bsum[blockIdx.x] = lds[t]; // block total
}

__global__ void k_scan2(int* __restrict__ bsum, int nblk){
  if (threadIdx.x == 0 && blockIdx.x == 0){
    int acc = 0;
    for (int b = 0; b < nblk; ++b){ int v = bsum[b]; bsum[b] = acc; acc += v; }
  }
}

__global__ __launch_bounds__(SCB)
void k_scan3(int* __restrict__ off, const int* __restrict__ bsum, int n, int ne){
  int i = blockIdx.x*SCB + threadIdx.x;
  if (i < n) off[i] += bsum[blockIdx.x];
  if (i == 0) off[n] = ne;
}

// atomic-free scatter: position precomputed in k_count; pure stream
__global__ __launch_bounds__(256)
void k_scatter(const int* __restrict__ src, const int* __restrict__ dst,
               const int* __restrict__ off, const int* __restrict__ pos,
               int* __restrict__ csr_src, int ne){
  int e = blockIdx.x*256 + threadIdx.x;
  if (e >= ne) return;
  int d = dst[e];
  csr_src[off[d] + pos[e]] = src[e];
}

// ============ Layer 1 GEMM via MFMA: fs(bf16) = h@Ws, fd(fp32) = h@Wd =======
// One mat per block (blockIdx.y), 64 nodes x 128 cols. h and W staged in LDS
// as bf16 (rows padded to 144 u16 = 288B -> 4-way LDS conflict, acceptable).
// Per wave: 16 nodes x 128 cols = 8 col-frags x 4 k-steps, 16x16x32 bf16 MFMA.
// C/D: col=lane&15, row=(lane>>4)*4+j (HW-verified mapping). A/B: row/col =
// lane&15, k = (lane>>4)*8+[0..7] (k-permutation-invariant between A and B).
typedef __attribute__((ext_vector_type(8))) short bf16x8;
typedef __attribute__((ext_vector_type(4))) float f32x4;

__global__ __launch_bounds__(256)
void k_gemm1m(const float* __restrict__ h, const float* __restrict__ Ws,
              const float* __restrict__ Wd, unsigned short* __restrict__ fs,
              float* __restrict__ fd, int n){
  __shared__ unsigned short hs[64][144];
  __shared__ unsigned short wsl[128][144];
  int tid = threadIdx.x;
  int node0 = blockIdx.x * 64;
  int mat = blockIdx.y;
  const float* W = mat ? Wd : Ws;
  for (int i = tid; i < 64*128; i += 256){
    int r = i >> 7, c = i & 127;
    int nd = node0 + r;
    hs[r][c] = f2bf((nd < n) ? h[(size_t)nd*128 + c] : 0.f);
  }
  for (int i = tid; i < 128*128; i += 256){
    int k = i >> 7, c = i & 127;
    wsl[c][k] = f2bf(W[i]);          // W transposed: wsl[col][k]
  }
  __syncthreads();
  int w = tid >> 6, lane = tid & 63;
  int rsel = lane & 15, ksel = (lane >> 4) * 8;
  f32x4 acc[8];
  #pragma unroll
  for (int cf = 0; cf < 8; ++cf){ acc[cf][0]=0.f; acc[cf][1]=0.f; acc[cf][2]=0.f; acc[cf][3]=0.f; }
  #pragma unroll
  for (int ks = 0; ks < 4; ++ks){
    bf16x8 a = *(const bf16x8*)&hs[w*16 + rsel][ks*32 + ksel];
    #pragma unroll
    for (int cf = 0; cf < 8; ++cf){
      bf16x8 b = *(const bf16x8*)&wsl[cf*16 + rsel][ks*32 + ksel];
      acc[cf] = __builtin_amdgcn_mfma_f32_16x16x32_bf16(a, b, acc[cf], 0, 0, 0);
    }
  }
  int rq = lane >> 4;
  #pragma unroll
  for (int cf = 0; cf < 8; ++cf){
    #pragma unroll
    for (int j = 0; j < 4; ++j){
      int nd = node0 + w*16 + rq*4 + j;
      int col = cf*16 + rsel;
      if (nd < n){
        if (mat == 0) fs[(size_t)nd*128 + col] = f2bf(acc[cf][j]);
        else          fd[(size_t)nd*128 + col] = acc[cf][j];
      }
    }
  }
}

// ============ Layer 1 fused: per-node online-softmax aggregate + ELU =========
// 32 lanes per edge, 4 dims per lane, gathers are bf16x4 (8 B/lane, uint2).
// Wave = 2 edges (half-waves); 4-step butterfly in 16-lane head groups;
// defer-max rescale; validity masks; halves merged at the end.
// NOTE: `fdv_` and `out` alias (fd1 reused as h1 output): wave-private rows.
#define THR1 10.f
__global__ __launch_bounds__(256)
void k_l1_node(const unsigned* __restrict__ fs, const float* fdv_,
               const int* __restrict__ off, const int* __restrict__ csr,
               const float* __restrict__ a1, float* out, int n){
  int wid  = (int)((blockIdx.x*256u + threadIdx.x) >> 6);
  int lane = threadIdx.x & 63;
  if (wid >= n) return;
  int d  = wid;
  int hh = lane >> 5;       // which edge of the pair
  int lp = lane & 31;       // dims 4lp..4lp+3 of the edge row
  int e0 = off[d], e1 = off[d+1];
  int deg = e1 - e0;
  const uint2* fs2v = (const uint2*)fs;     // row = 32 uint2
  float4 fdv = ((const float4*)fdv_)[(size_t)d*32 + lp];
  float4 aw  = ((const float4*)a1)[lp];
  float m = FNEG_MAX, den = 0.f;
  float4 acc = make_float4(0.f, 0.f, 0.f, 0.f);

  int nt = (deg + 3) & ~3;   // multiple of 4 edges (2 iters of 2)
  for (int k = 0; k < nt; k += 4){
    int eiA = e0 + k + hh;
    int eiB = eiA + 2;
    bool vA = eiA < e1, vB = eiB < e1;
    int sA = csr[vA ? eiA : e0];
    int sB = csr[vB ? eiB : e0];
    uint2 uA = fs2v[(size_t)sA*32 + lp];
    uint2 uB = fs2v[(size_t)sB*32 + lp];
    float xA0 = bflo(uA.x), xA1 = bfhi(uA.x), xA2 = bflo(uA.y), xA3 = bfhi(uA.y);
    float xB0 = bflo(uB.x), xB1 = bfhi(uB.x), xB2 = bflo(uB.y), xB3 = bfhi(uB.y);
    float pA, pB;
    {
      float t0 = xA0 + fdv.x, t1 = xA1 + fdv.y;
      float t2 = xA2 + fdv.z, t3 = xA3 + fdv.w;
      t0 = fmaxf(t0, NEG*t0); t1 = fmaxf(t1, NEG*t1);
      t2 = fmaxf(t2, NEG*t2); t3 = fmaxf(t3, NEG*t3);
      pA = fmaf(t0, aw.x, fmaf(t1, aw.y, fmaf(t2, aw.z, t3*aw.w)));
    }
    {
      float t0 = xB0 + fdv.x, t1 = xB1 + fdv.y;
      float t2 = xB2 + fdv.z, t3 = xB3 + fdv.w;
      t0 = fmaxf(t0, NEG*t0); t1 = fmaxf(t1, NEG*t1);
      t2 = fmaxf(t2, NEG*t2); t3 = fmaxf(t3, NEG*t3);
      pB = fmaf(t0, aw.x, fmaf(t1, aw.y, fmaf(t2, aw.z, t3*aw.w)));
    }
    // 4-step butterfly within 16-lane head groups; both edges in parallel
    #pragma unroll
    for (int o = 8; o >= 1; o >>= 1){
      pA += __shfl_xor(pA, o, 64);
      pB += __shfl_xor(pB, o, 64);
    }
    pA = vA ? pA : FNEG_MAX;
    pB = vB ? pB : FNEG_MAX;
    float pmax = fmaxf(pA, pB);
    if (__any(pmax > m + THR1)){         // rare rescale
      float nm = fmaxf(m, pmax);
      float sc = __expf(m - nm);         // m==FNEG_MAX -> exp underflows to 0
      den *= sc;
      acc.x *= sc; acc.y *= sc; acc.z *= sc; acc.w *= sc;
      m = nm;
    }
    float wA = vA ? __expf(pA - m) : 0.f;
    float wB = vB ? __expf(pB - m) : 0.f;
    den += wA + wB;
    acc.x = fmaf(wA, xA0, fmaf(wB, xB0, acc.x));
    acc.y = fmaf(wA, xA1, fmaf(wB, xB1, acc.y));
    acc.z = fmaf(wA, xA2, fmaf(wB, xB2, acc.z));
    acc.w = fmaf(wA, xA3, fmaf(wB, xB3, acc.w));
  }

  // merge the two half-wave partials
  float om   = __shfl_xor(m,   32, 64);
  float oden = __shfl_xor(den, 32, 64);
  float4 oacc;
  oacc.x = __shfl_xor(acc.x, 32, 64);
  oacc.y = __shfl_xor(acc.y, 32, 64);
  oacc.z = __shfl_xor(acc.z, 32, 64);
  oacc.w = __shfl_xor(acc.w, 32, 64);
  float nm = fmaxf(m, om);
  float s1 = __expf(m - nm), s2 = __expf(om - nm);
  den = den*s1 + oden*s2;
  float4 r;
  r.x = acc.x*s1 + oacc.x*s2;
  r.y = acc.y*s1 + oacc.y*s2;
  r.z = acc.z*s1 + oacc.z*s2;
  r.w = acc.w*s1 + oacc.w*s2;
  float inv = (den > 0.f) ? 1.f/den : 0.f;
  r.x *= inv; r.y *= inv; r.z *= inv; r.w *= inv;
  r.x = r.x > 0.f ? r.x : __expf(r.x) - 1.f;   // ELU fused
  r.y = r.y > 0.f ? r.y : __expf(r.y) - 1.f;
  r.z = r.z > 0.f ? r.z : __expf(r.z) - 1.f;
  r.w = r.w > 0.f ? r.w : __expf(r.w) - 1.f;
  if (hh == 0) ((float4*)out)[(size_t)d*32 + lp] = r;
}

// ============ Layer 2 GEMM: fs2(bf16)/fd2/res = h1 @ {W2s,W2d,Wr} ===========
__global__ __launch_bounds__(256)
void k_gemm2(const float* __restrict__ h1, const float* __restrict__ Ws,
             const float* __restrict__ Wd, const float* __restrict__ Wr,
             unsigned short* __restrict__ fs2, float* __restrict__ fd2,
             float* __restrict__ res, int n){
  __shared__ float hs[16][129];
  __shared__ float w[3][128][16];
  int tid = threadIdx.x;
  for (int i = tid; i < 2048; i += 256){
    int k = i >> 4, j = i & 15;
    w[0][k][j] = Ws[i]; w[1][k][j] = Wd[i]; w[2][k][j] = Wr[i];
  }
  int node0 = blockIdx.x * 16;
  for (int i = tid; i < 2048; i += 256){
    int r = i >> 7, c = i & 127;
    int nd = node0 + r;
    hs[r][c] = (nd < n) ? h1[(size_t)nd*128 + c] : 0.f;
  }
  __syncthreads();
  int j = tid & 15, ni = tid >> 4;
  float as = 0.f, ad = 0.f, ar = 0.f;
  for (int k = 0; k < 128; ++k){
    float hv = hs[ni][k];
    as = fmaf(hv, w[0][k][j], as);
    ad = fmaf(hv, w[1][k][j], ad);
    ar = fmaf(hv, w[2][k][j], ar);
  }
  int nd = node0 + ni;
  if (nd < n){
    fs2[(size_t)nd*16 + j] = f2bf(as);
    fd2[(size_t)nd*16 + j] = ad;
    res[(size_t)nd*16 + j] = ar;
  }
}

// ============ Layer 2 fused: per-node online softmax + residual -> d_out =====
#define THR2 10.f
__global__ __launch_bounds__(256)
void k_l2_node(const unsigned short* __restrict__ fs2, const float* __restrict__ fd2,
               const float* __restrict__ resd, const int* __restrict__ off,
               const int* __restrict__ csr, const float* __restrict__ a2,
               float* __restrict__ outp, int n){
  int wid  = (int)((blockIdx.x*256u + threadIdx.x) >> 6);
  int lane = threadIdx.x & 63;
  if (wid >= n) return;
  int d = wid;
  int g = lane >> 4, j = lane & 15;
  int e0 = off[d], e1 = off[d+1];
  int deg = e1 - e0;
  float fdv = fd2[(size_t)d*16 + j];
  float aw  = a2[j];
  float m = FNEG_MAX, den = 0.f, acc = 0.f;
  int jmax = (deg + 7) >> 3;           // wave-uniform trip count
  for (int it = 0; it < jmax; ++it){
    int iA = e0 + it*8 + g;
    int iB = iA + 4;
    bool vA = iA < e1, vB = iB < e1;
    int sA = csr[vA ? iA : e0];
    int sB = csr[vB ? iB : e0];
    float xA = __uint_as_float((unsigned)fs2[(size_t)sA*16 + j] << 16);
    float xB = __uint_as_float((unsigned)fs2[(size_t)sB*16 + j] << 16);
    float tA = xA + fdv; tA = fmaxf(tA, NEG*tA);
    float tB = xB + fdv; tB = fmaxf(tB, NEG*tB);
    float pA = tA * aw, pB = tB * aw;
    #pragma unroll
    for (int o = 8; o >= 1; o >>= 1){
      pA += __shfl_xor(pA, o, 64);
      pB += __shfl_xor(pB, o, 64);
    }
    pA = vA ? pA : FNEG_MAX;
    pB = vB ? pB : FNEG_MAX;
    float pmax = fmaxf(pA, pB);
    if (__any(pmax > m + THR2)){       // rare rescale
      float nm = fmaxf(m, pmax);
      float sc = __expf(m - nm);
      den *= sc; acc *= sc;
      m = nm;
    }
    float wA = vA ? __expf(pA - m) : 0.f;
    float wB = vB ? __expf(pB - m) : 0.f;
    den += wA + wB;
    acc = fmaf(wA, xA, fmaf(wB, xB, acc));
  }
  // merge the 4 groups' (m, den, acc): butterfly xor 16 then 32
  #pragma unroll
  for (int o = 16; o <= 32; o <<= 1){
    float om   = __shfl_xor(m,   o, 64);
    float oden = __shfl_xor(den, o, 64);
    float oacc = __shfl_xor(acc, o, 64);
    float nm = fmaxf(m, om);
    float s1 = __expf(m - nm);
    float s2 = __expf(om - nm);
    den = den*s1 + oden*s2;
    acc = acc*s1 + oacc*s2;
    m = nm;
  }
  if (g == 0){
    float inv = (den > 0.f) ? 1.f/den : 0.f;
    outp[(size_t)d*16 + j] = acc*inv + resd[(size_t)d*16 + j];
  }
}

extern "C" void kernel_launch(void* const* d_in, const int* in_sizes, int n_in,
                              void* d_out, int out_size, void* d_ws, size_t ws_size,
                              hipStream_t stream) {
  const float* h    = (const float*)d_in[0];
  const int*   src  = (const int*)  d_in[1];
  const int*   dst  = (const int*)  d_in[2];
  const float* W1s  = (const float*)d_in[3];
  const float* W1d  = (const float*)d_in[4];
  const float* a1   = (const float*)d_in[5];
  const float* W2s  = (const float*)d_in[6];
  const float* W2d  = (const float*)d_in[7];
  const float* a2   = (const float*)d_in[8];
  const float* Wres = (const float*)d_in[9];
  float* out = (float*)d_out;

  const int n  = in_sizes[0] / 128;   // 50000
  const int ne = in_sizes[1];         // 1600000

  // ---- workspace layout ----
  float* ws  = (float*)d_ws;
  float* fs1 = ws;                         // n*128 region (bf16 uses n*64 uints)
  float* fd1 = fs1 + (size_t)n*128;        // n*128 (becomes h1 in k_l1_node)
  float* fs2 = fd1 + (size_t)n*128;        // n*16 region (bf16 uses n*8 floats)
  float* fd2 = fs2 + (size_t)n*16;         // n*16
  float* res = fd2 + (size_t)n*16;         // n*16
  int* deg     = (int*)(res + (size_t)n*16); // n
  int* off     = deg + n;                    // n+1
  int* pos     = off + (n+1);                // ne (per-edge intra-node slot)
  int* bsum    = pos + ne;                   // scan block sums (<= 128)
  int* csr_src = bsum + 128;                 // ne

  const int nblk = (n + SCB - 1) / SCB;

  // ---- CSR build ----
  hipMemsetAsync(deg, 0, (size_t)n*4, stream);
  k_count  <<<(ne + 255)/256, 256, 0, stream>>>(dst, deg, pos, ne);
  k_scan1  <<<nblk, SCB, 0, stream>>>(deg, off, bsum, n);
  k_scan2  <<<1, 64, 0, stream>>>(bsum, nblk);
  k_scan3  <<<nblk, SCB, 0, stream>>>(off, bsum, n, ne);
  k_scatter<<<(ne + 255)/256, 256, 0, stream>>>(src, dst, off, pos, csr_src, ne);

  // ---- layer 1 (MFMA gemm) ----
  k_gemm1m <<<dim3((n + 63)/64, 2), 256, 0, stream>>>(
      h, W1s, W1d, (unsigned short*)fs1, fd1, n);
  k_l1_node<<<(n + 3)/4, 256, 0, stream>>>((const unsigned*)fs1, fd1, off, csr_src, a1, fd1, n);

  // ---- layer 2 (writes d_out directly) ----
  k_gemm2  <<<(n + 15)/16, 256, 0, stream>>>(fd1, W2s, W2d, Wres, (unsigned short*)fs2, fd2, res, n);
  k_l2_node<<<(n + 3)/4, 256, 0, stream>>>((const unsigned short*)fs2, fd2, res, off, csr_src, a2, out, n);
}

// Round 22
// 302.290 us; speedup vs baseline: 1.0667x; 1.0667x over previous
//
#include <hip/hip_runtime.h>
#include <hip/hip_bf16.h>

#define NEG 0.2f
#define FNEG_MAX -3.402823466e38f

// round-to-nearest-even fp32 -> bf16 (as u16)
__device__ __forceinline__ unsigned short f2bf(float f){
  unsigned u = __float_as_uint(f);
  return (unsigned short)((u + 0x7fffu + ((u >> 16) & 1u)) >> 16);
}
__device__ __forceinline__ unsigned pk2bf(float a, float b){
  return (unsigned)f2bf(a) | ((unsigned)f2bf(b) << 16);
}
__device__ __forceinline__ float bflo(unsigned u){ return __uint_as_float(u << 16); }
__device__ __forceinline__ float bfhi(unsigned u){ return __uint_as_float(u & 0xffff0000u); }

// ============ CSR build: degree count + per-edge position (atomic ret) ======
__global__ __launch_bounds__(256)
void k_count(const int* __restrict__ dst, int* __restrict__ deg,
             int* __restrict__ pos, int ne){
  int e = blockIdx.x*256 + threadIdx.x;
  if (e < ne) pos[e] = atomicAdd(&deg[dst[e]], 1);
}

#define SCB 512
__global__ __launch_bounds__(SCB)
void k_scan1(const int* __restrict__ deg, int* __restrict__ off,
             int* __restrict__ bsum, int n){
  __shared__ int lds[SCB];
  int t = threadIdx.x, i = blockIdx.x*SCB + t;
  int x = (i < n) ? deg[i] : 0;
  lds[t] = x; __syncthreads();
  for (int s = 1; s < SCB; s <<= 1){
    int v = (t >= s) ? lds[t-s] : 0;
    __syncthreads();
    lds[t] += v;
    __syncthreads();
  }
  if (i < n) off[i] = lds[t] - x;            // exclusive
  if (t == SCB-1) bsum[blockIdx.x] = lds[t]; // block total
}

__global__ void k_scan2(int* __restrict__ bsum, int nblk){
  if (threadIdx.x == 0 && blockIdx.x == 0){
    int acc = 0;
    for (int b = 0; b < nblk; ++b){ int v = bsum[b]; bsum[b] = acc; acc += v; }
  }
}

__global__ __launch_bounds__(SCB)
void k_scan3(int* __restrict__ off, const int* __restrict__ bsum, int n, int ne){
  int i = blockIdx.x*SCB + threadIdx.x;
  if (i < n) off[i] += bsum[blockIdx.x];
  if (i == 0) off[n] = ne;
}

// atomic-free scatter: position precomputed in k_count; pure stream
__global__ __launch_bounds__(256)
void k_scatter(const int* __restrict__ src, const int* __restrict__ dst,
               const int* __restrict__ off, const int* __restrict__ pos,
               int* __restrict__ csr_src, int ne){
  int e = blockIdx.x*256 + threadIdx.x;
  if (e >= ne) return;
  int d = dst[e];
  csr_src[off[d] + pos[e]] = src[e];
}

// ============ Prep: h -> bf16 hbf; W1s/W1d -> bf16 TRANSPOSED wt[mat][c][k] ==
// One-time conversion/transpose so the MFMA gemm does zero per-block staging.
__global__ __launch_bounds__(256)
void k_prep(const float* __restrict__ h, const float* __restrict__ Ws,
            const float* __restrict__ Wd, unsigned* __restrict__ hbf,
            unsigned short* __restrict__ wt, int n){
  int i = blockIdx.x*256 + threadIdx.x;
  int nh = n*32;                       // h as float4 items
  if (i < nh){
    float4 v = ((const float4*)h)[i];
    uint2 o; o.x = pk2bf(v.x, v.y); o.y = pk2bf(v.z, v.w);
    ((uint2*)hbf)[i] = o;
  } else {
    int j = i - nh;
    if (j < 2*16384){
      int mat = j >> 14, kc = j & 16383;
      int k = kc >> 7, c = kc & 127;
      const float* W = mat ? Wd : Ws;
      wt[(size_t)mat*16384 + (size_t)c*128 + k] = f2bf(W[kc]);
    }
  }
}

// ============ Layer 1 GEMM via MFMA, LDS-free ===============================
// fs(bf16) = h@Ws, fd(fp32) = h@Wd. One mat per blockIdx.y; 64 nodes/block;
// wave = 16 nodes x 128 cols = 8 col-frags x 4 k-steps of 16x16x32 bf16 MFMA.
// Both operands are contiguous 16B global loads: A from hbf (bf16 h rows),
// B from wt (bf16 W pre-transposed, L1-resident 32KB/mat). C/D mapping:
// col=lane&15, row=(lane>>4)*4+j (HW-verified). A/B share lane->k mapping
// (k-permutation-invariant). OOB node rows: clamped address (finite, unstored).
typedef __attribute__((ext_vector_type(8))) short bf16x8;
typedef __attribute__((ext_vector_type(4))) float f32x4;

__global__ __launch_bounds__(256)
void k_gemm1m(const unsigned short* __restrict__ hbf,
              const unsigned short* __restrict__ wt,
              unsigned short* __restrict__ fs, float* __restrict__ fd, int n){
  int tid = threadIdx.x;
  int node0 = blockIdx.x * 64;
  int mat = blockIdx.y;
  const unsigned short* W = wt + (size_t)mat*16384;
  int w = tid >> 6, lane = tid & 63;
  int rsel = lane & 15, ksel = (lane >> 4) * 8;
  int nd_a = node0 + w*16 + rsel;
  int nda = nd_a < n ? nd_a : n-1;              // clamp: garbage rows unstored
  const unsigned short* arow = hbf + (size_t)nda*128;

  bf16x8 a[4];
  #pragma unroll
  for (int ks = 0; ks < 4; ++ks)
    a[ks] = *(const bf16x8*)&arow[ks*32 + ksel];

  f32x4 acc[8];
  #pragma unroll
  for (int cf = 0; cf < 8; ++cf){ acc[cf][0]=0.f; acc[cf][1]=0.f; acc[cf][2]=0.f; acc[cf][3]=0.f; }
  #pragma unroll
  for (int cf = 0; cf < 8; ++cf){
    const unsigned short* brow = W + (size_t)(cf*16 + rsel)*128;
    #pragma unroll
    for (int ks = 0; ks < 4; ++ks){
      bf16x8 b = *(const bf16x8*)&brow[ks*32 + ksel];
      acc[cf] = __builtin_amdgcn_mfma_f32_16x16x32_bf16(a[ks], b, acc[cf], 0, 0, 0);
    }
  }
  int rq = lane >> 4;
  #pragma unroll
  for (int cf = 0; cf < 8; ++cf){
    #pragma unroll
    for (int j = 0; j < 4; ++j){
      int nd = node0 + w*16 + rq*4 + j;
      int col = cf*16 + rsel;
      if (nd < n){
        if (mat == 0) fs[(size_t)nd*128 + col] = f2bf(acc[cf][j]);
        else          fd[(size_t)nd*128 + col] = acc[cf][j];
      }
    }
  }
}

// ============ Layer 1 fused: per-node online-softmax aggregate + ELU =========
// 32 lanes per edge, 4 dims per lane, gathers are bf16x4 (8 B/lane, uint2).
// Wave = 2 edges (half-waves); 4-step butterfly in 16-lane head groups;
// defer-max rescale; validity masks; halves merged at the end.
// NOTE: `fdv_` and `out` alias (fd1 reused as h1 output): wave-private rows.
#define THR1 10.f
__global__ __launch_bounds__(256)
void k_l1_node(const unsigned* __restrict__ fs, const float* fdv_,
               const int* __restrict__ off, const int* __restrict__ csr,
               const float* __restrict__ a1, float* out, int n){
  int wid  = (int)((blockIdx.x*256u + threadIdx.x) >> 6);
  int lane = threadIdx.x & 63;
  if (wid >= n) return;
  int d  = wid;
  int hh = lane >> 5;       // which edge of the pair
  int lp = lane & 31;       // dims 4lp..4lp+3 of the edge row
  int e0 = off[d], e1 = off[d+1];
  int deg = e1 - e0;
  const uint2* fs2v = (const uint2*)fs;     // row = 32 uint2
  float4 fdv = ((const float4*)fdv_)[(size_t)d*32 + lp];
  float4 aw  = ((const float4*)a1)[lp];
  float m = FNEG_MAX, den = 0.f;
  float4 acc = make_float4(0.f, 0.f, 0.f, 0.f);

  int nt = (deg + 3) & ~3;   // multiple of 4 edges (2 iters of 2)
  for (int k = 0; k < nt; k += 4){
    int eiA = e0 + k + hh;
    int eiB = eiA + 2;
    bool vA = eiA < e1, vB = eiB < e1;
    int sA = csr[vA ? eiA : e0];
    int sB = csr[vB ? eiB : e0];
    uint2 uA = fs2v[(size_t)sA*32 + lp];
    uint2 uB = fs2v[(size_t)sB*32 + lp];
    float xA0 = bflo(uA.x), xA1 = bfhi(uA.x), xA2 = bflo(uA.y), xA3 = bfhi(uA.y);
    float xB0 = bflo(uB.x), xB1 = bfhi(uB.x), xB2 = bflo(uB.y), xB3 = bfhi(uB.y);
    float pA, pB;
    {
      float t0 = xA0 + fdv.x, t1 = xA1 + fdv.y;
      float t2 = xA2 + fdv.z, t3 = xA3 + fdv.w;
      t0 = fmaxf(t0, NEG*t0); t1 = fmaxf(t1, NEG*t1);
      t2 = fmaxf(t2, NEG*t2); t3 = fmaxf(t3, NEG*t3);
      pA = fmaf(t0, aw.x, fmaf(t1, aw.y, fmaf(t2, aw.z, t3*aw.w)));
    }
    {
      float t0 = xB0 + fdv.x, t1 = xB1 + fdv.y;
      float t2 = xB2 + fdv.z, t3 = xB3 + fdv.w;
      t0 = fmaxf(t0, NEG*t0); t1 = fmaxf(t1, NEG*t1);
      t2 = fmaxf(t2, NEG*t2); t3 = fmaxf(t3, NEG*t3);
      pB = fmaf(t0, aw.x, fmaf(t1, aw.y, fmaf(t2, aw.z, t3*aw.w)));
    }
    // 4-step butterfly within 16-lane head groups; both edges in parallel
    #pragma unroll
    for (int o = 8; o >= 1; o >>= 1){
      pA += __shfl_xor(pA, o, 64);
      pB += __shfl_xor(pB, o, 64);
    }
    pA = vA ? pA : FNEG_MAX;
    pB = vB ? pB : FNEG_MAX;
    float pmax = fmaxf(pA, pB);
    if (__any(pmax > m + THR1)){         // rare rescale
      float nm = fmaxf(m, pmax);
      float sc = __expf(m - nm);         // m==FNEG_MAX -> exp underflows to 0
      den *= sc;
      acc.x *= sc; acc.y *= sc; acc.z *= sc; acc.w *= sc;
      m = nm;
    }
    float wA = vA ? __expf(pA - m) : 0.f;
    float wB = vB ? __expf(pB - m) : 0.f;
    den += wA + wB;
    acc.x = fmaf(wA, xA0, fmaf(wB, xB0, acc.x));
    acc.y = fmaf(wA, xA1, fmaf(wB, xB1, acc.y));
    acc.z = fmaf(wA, xA2, fmaf(wB, xB2, acc.z));
    acc.w = fmaf(wA, xA3, fmaf(wB, xB3, acc.w));
  }

  // merge the two half-wave partials
  float om   = __shfl_xor(m,   32, 64);
  float oden = __shfl_xor(den, 32, 64);
  float4 oacc;
  oacc.x = __shfl_xor(acc.x, 32, 64);
  oacc.y = __shfl_xor(acc.y, 32, 64);
  oacc.z = __shfl_xor(acc.z, 32, 64);
  oacc.w = __shfl_xor(acc.w, 32, 64);
  float nm = fmaxf(m, om);
  float s1 = __expf(m - nm), s2 = __expf(om - nm);
  den = den*s1 + oden*s2;
  float4 r;
  r.x = acc.x*s1 + oacc.x*s2;
  r.y = acc.y*s1 + oacc.y*s2;
  r.z = acc.z*s1 + oacc.z*s2;
  r.w = acc.w*s1 + oacc.w*s2;
  float inv = (den > 0.f) ? 1.f/den : 0.f;
  r.x *= inv; r.y *= inv; r.z *= inv; r.w *= inv;
  r.x = r.x > 0.f ? r.x : __expf(r.x) - 1.f;   // ELU fused
  r.y = r.y > 0.f ? r.y : __expf(r.y) - 1.f;
  r.z = r.z > 0.f ? r.z : __expf(r.z) - 1.f;
  r.w = r.w > 0.f ? r.w : __expf(r.w) - 1.f;
  if (hh == 0) ((float4*)out)[(size_t)d*32 + lp] = r;
}

// ============ Layer 2 GEMM: fs2(bf16)/fd2/res = h1 @ {W2s,W2d,Wr} ===========
__global__ __launch_bounds__(256)
void k_gemm2(const float* __restrict__ h1, const float* __restrict__ Ws,
             const float* __restrict__ Wd, const float* __restrict__ Wr,
             unsigned short* __restrict__ fs2, float* __restrict__ fd2,
             float* __restrict__ res, int n){
  __shared__ float hs[16][129];
  __shared__ float w[3][128][16];
  int tid = threadIdx.x;
  for (int i = tid; i < 2048; i += 256){
    int k = i >> 4, j = i & 15;
    w[0][k][j] = Ws[i]; w[1][k][j] = Wd[i]; w[2][k][j] = Wr[i];
  }
  int node0 = blockIdx.x * 16;
  for (int i = tid; i < 2048; i += 256){
    int r = i >> 7, c = i & 127;
    int nd = node0 + r;
    hs[r][c] = (nd < n) ? h1[(size_t)nd*128 + c] : 0.f;
  }
  __syncthreads();
  int j = tid & 15, ni = tid >> 4;
  float as = 0.f, ad = 0.f, ar = 0.f;
  for (int k = 0; k < 128; ++k){
    float hv = hs[ni][k];
    as = fmaf(hv, w[0][k][j], as);
    ad = fmaf(hv, w[1][k][j], ad);
    ar = fmaf(hv, w[2][k][j], ar);
  }
  int nd = node0 + ni;
  if (nd < n){
    fs2[(size_t)nd*16 + j] = f2bf(as);
    fd2[(size_t)nd*16 + j] = ad;
    res[(size_t)nd*16 + j] = ar;
  }
}

// ============ Layer 2 fused: per-node online softmax + residual -> d_out =====
#define THR2 10.f
__global__ __launch_bounds__(256)
void k_l2_node(const unsigned short* __restrict__ fs2, const float* __restrict__ fd2,
               const float* __restrict__ resd, const int* __restrict__ off,
               const int* __restrict__ csr, const float* __restrict__ a2,
               float* __restrict__ outp, int n){
  int wid  = (int)((blockIdx.x*256u + threadIdx.x) >> 6);
  int lane = threadIdx.x & 63;
  if (wid >= n) return;
  int d = wid;
  int g = lane >> 4, j = lane & 15;
  int e0 = off[d], e1 = off[d+1];
  int deg = e1 - e0;
  float fdv = fd2[(size_t)d*16 + j];
  float aw  = a2[j];
  float m = FNEG_MAX, den = 0.f, acc = 0.f;
  int jmax = (deg + 7) >> 3;           // wave-uniform trip count
  for (int it = 0; it < jmax; ++it){
    int iA = e0 + it*8 + g;
    int iB = iA + 4;
    bool vA = iA < e1, vB = iB < e1;
    int sA = csr[vA ? iA : e0];
    int sB = csr[vB ? iB : e0];
    float xA = __uint_as_float((unsigned)fs2[(size_t)sA*16 + j] << 16);
    float xB = __uint_as_float((unsigned)fs2[(size_t)sB*16 + j] << 16);
    float tA = xA + fdv; tA = fmaxf(tA, NEG*tA);
    float tB = xB + fdv; tB = fmaxf(tB, NEG*tB);
    float pA = tA * aw, pB = tB * aw;
    #pragma unroll
    for (int o = 8; o >= 1; o >>= 1){
      pA += __shfl_xor(pA, o, 64);
      pB += __shfl_xor(pB, o, 64);
    }
    pA = vA ? pA : FNEG_MAX;
    pB = vB ? pB : FNEG_MAX;
    float pmax = fmaxf(pA, pB);
    if (__any(pmax > m + THR2)){       // rare rescale
      float nm = fmaxf(m, pmax);
      float sc = __expf(m - nm);
      den *= sc; acc *= sc;
      m = nm;
    }
    float wA = vA ? __expf(pA - m) : 0.f;
    float wB = vB ? __expf(pB - m) : 0.f;
    den += wA + wB;
    acc = fmaf(wA, xA, fmaf(wB, xB, acc));
  }
  // merge the 4 groups' (m, den, acc): butterfly xor 16 then 32
  #pragma unroll
  for (int o = 16; o <= 32; o <<= 1){
    float om   = __shfl_xor(m,   o, 64);
    float oden = __shfl_xor(den, o, 64);
    float oacc = __shfl_xor(acc, o, 64);
    float nm = fmaxf(m, om);
    float s1 = __expf(m - nm);
    float s2 = __expf(om - nm);
    den = den*s1 + oden*s2;
    acc = acc*s1 + oacc*s2;
    m = nm;
  }
  if (g == 0){
    float inv = (den > 0.f) ? 1.f/den : 0.f;
    outp[(size_t)d*16 + j] = acc*inv + resd[(size_t)d*16 + j];
  }
}

extern "C" void kernel_launch(void* const* d_in, const int* in_sizes, int n_in,
                              void* d_out, int out_size, void* d_ws, size_t ws_size,
                              hipStream_t stream) {
  const float* h    = (const float*)d_in[0];
  const int*   src  = (const int*)  d_in[1];
  const int*   dst  = (const int*)  d_in[2];
  const float* W1s  = (const float*)d_in[3];
  const float* W1d  = (const float*)d_in[4];
  const float* a1   = (const float*)d_in[5];
  const float* W2s  = (const float*)d_in[6];
  const float* W2d  = (const float*)d_in[7];
  const float* a2   = (const float*)d_in[8];
  const float* Wres = (const float*)d_in[9];
  float* out = (float*)d_out;

  const int n  = in_sizes[0] / 128;   // 50000
  const int ne = in_sizes[1];         // 1600000

  // ---- workspace layout ----
  // fs1 region is n*128 floats; fs bf16 uses first half, hbf uses second half.
  float* ws  = (float*)d_ws;
  float* fs1 = ws;                         // n*64 floats: fs bf16 (n*128 u16)
  unsigned* hbf = (unsigned*)(fs1 + (size_t)n*64);   // n*64 uints: h in bf16
  float* fd1 = fs1 + (size_t)n*128;        // n*128 (becomes h1 in k_l1_node)
  float* fs2 = fd1 + (size_t)n*128;        // n*16 region (bf16 uses n*8 floats)
  float* fd2 = fs2 + (size_t)n*16;         // n*16
  float* res = fd2 + (size_t)n*16;         // n*16
  int* deg     = (int*)(res + (size_t)n*16); // n
  int* off     = deg + n;                    // n+1
  int* pos     = off + (n+1);                // ne (per-edge intra-node slot)
  int* bsum    = pos + ne;                   // scan block sums (<= 128)
  int* csr_src = bsum + 128;                 // ne
  unsigned short* wt = (unsigned short*)(csr_src + ne); // 2*16384 u16 (64KB)

  const int nblk = (n + SCB - 1) / SCB;

  // ---- CSR build ----
  hipMemsetAsync(deg, 0, (size_t)n*4, stream);
  k_count  <<<(ne + 255)/256, 256, 0, stream>>>(dst, deg, pos, ne);
  k_scan1  <<<nblk, SCB, 0, stream>>>(deg, off, bsum, n);
  k_scan2  <<<1, 64, 0, stream>>>(bsum, nblk);
  k_scan3  <<<nblk, SCB, 0, stream>>>(off, bsum, n, ne);
  k_scatter<<<(ne + 255)/256, 256, 0, stream>>>(src, dst, off, pos, csr_src, ne);

  // ---- layer 1 (prep once, then LDS-free MFMA gemm) ----
  int prep_items = n*32 + 2*16384;
  k_prep   <<<(prep_items + 255)/256, 256, 0, stream>>>(h, W1s, W1d, hbf, wt, n);
  k_gemm1m <<<dim3((n + 63)/64, 2), 256, 0, stream>>>(
      (const unsigned short*)hbf, wt, (unsigned short*)fs1, fd1, n);
  k_l1_node<<<(n + 3)/4, 256, 0, stream>>>((const unsigned*)fs1, fd1, off, csr_src, a1, fd1, n);

  // ---- layer 2 (writes d_out directly) ----
  k_gemm2  <<<(n + 15)/16, 256, 0, stream>>>(fd1, W2s, W2d, Wres, (unsigned short*)fs2, fd2, res, n);
  k_l2_node<<<(n + 3)/4, 256, 0, stream>>>((const unsigned short*)fs2, fd2, res, off, csr_src, a2, out, n);
}

// Round 24
// 301.768 us; speedup vs baseline: 1.0686x; 1.0017x over previous
//
#include <hip/hip_runtime.h>
#include <hip/hip_bf16.h>

#define NEG 0.2f
#define FNEG_MAX -3.402823466e38f

// round-to-nearest-even fp32 -> bf16 (as u16)
__device__ __forceinline__ unsigned short f2bf(float f){
  unsigned u = __float_as_uint(f);
  return (unsigned short)((u + 0x7fffu + ((u >> 16) & 1u)) >> 16);
}
__device__ __forceinline__ unsigned pk2bf(float a, float b){
  return (unsigned)f2bf(a) | ((unsigned)f2bf(b) << 16);
}
__device__ __forceinline__ float bflo(unsigned u){ return __uint_as_float(u << 16); }
__device__ __forceinline__ float bfhi(unsigned u){ return __uint_as_float(u & 0xffff0000u); }

// ============ CSR build: degree count + per-edge position (atomic ret) ======
__global__ __launch_bounds__(256)
void k_count(const int* __restrict__ dst, int* __restrict__ deg,
             int* __restrict__ pos, int ne){
  int e = blockIdx.x*256 + threadIdx.x;
  if (e < ne) pos[e] = atomicAdd(&deg[dst[e]], 1);
}

#define SCB 512
__global__ __launch_bounds__(SCB)
void k_scan1(const int* __restrict__ deg, int* __restrict__ off,
             int* __restrict__ bsum, int n){
  __shared__ int lds[SCB];
  int t = threadIdx.x, i = blockIdx.x*SCB + t;
  int x = (i < n) ? deg[i] : 0;
  lds[t] = x; __syncthreads();
  for (int s = 1; s < SCB; s <<= 1){
    int v = (t >= s) ? lds[t-s] : 0;
    __syncthreads();
    lds[t] += v;
    __syncthreads();
  }
  if (i < n) off[i] = lds[t] - x;            // exclusive
  if (t == SCB-1) bsum[blockIdx.x] = lds[t]; // block total
}

__global__ void k_scan2(int* __restrict__ bsum, int nblk){
  if (threadIdx.x == 0 && blockIdx.x == 0){
    int acc = 0;
    for (int b = 0; b < nblk; ++b){ int v = bsum[b]; bsum[b] = acc; acc += v; }
  }
}

__global__ __launch_bounds__(SCB)
void k_scan3(int* __restrict__ off, const int* __restrict__ bsum, int n, int ne){
  int i = blockIdx.x*SCB + threadIdx.x;
  if (i < n) off[i] += bsum[blockIdx.x];
  if (i == 0) off[n] = ne;
}

// atomic-free scatter; csr_src stored as u16 (node ids < 65536) -> halves
// the random-store write traffic (write-amp bound, round 18/19 analysis).
__global__ __launch_bounds__(256)
void k_scatter(const int* __restrict__ src, const int* __restrict__ dst,
               const int* __restrict__ off, const int* __restrict__ pos,
               unsigned short* __restrict__ csr_src, int ne){
  int e = blockIdx.x*256 + threadIdx.x;
  if (e >= ne) return;
  int d = dst[e];
  csr_src[off[d] + pos[e]] = (unsigned short)src[e];
}

// ============ Prep: h -> bf16 hbf; W1s/W1d -> bf16 TRANSPOSED wt[mat][c][k] ==
__global__ __launch_bounds__(256)
void k_prep(const float* __restrict__ h, const float* __restrict__ Ws,
            const float* __restrict__ Wd, unsigned* __restrict__ hbf,
            unsigned short* __restrict__ wt, int n){
  int i = blockIdx.x*256 + threadIdx.x;
  int nh = n*32;                       // h as float4 items
  if (i < nh){
    float4 v = ((const float4*)h)[i];
    uint2 o; o.x = pk2bf(v.x, v.y); o.y = pk2bf(v.z, v.w);
    ((uint2*)hbf)[i] = o;
  } else {
    int j = i - nh;
    if (j < 2*16384){
      int mat = j >> 14, kc = j & 16383;
      int k = kc >> 7, c = kc & 127;
      const float* W = mat ? Wd : Ws;
      wt[(size_t)mat*16384 + (size_t)c*128 + k] = f2bf(W[kc]);
    }
  }
}

// ============ Layer 1 GEMM via MFMA, LDS-free ===============================
// fs(bf16) = h@Ws, fd(fp32) = h@Wd. One mat per blockIdx.y; 64 nodes/block;
// wave = 16 nodes x 128 cols = 8 col-frags x 4 k-steps of 16x16x32 bf16 MFMA.
// Both operands are contiguous 16B global loads: A from hbf (bf16 h rows),
// B from wt (bf16 W pre-transposed, L1-resident 32KB/mat). C/D mapping:
// col=lane&15, row=(lane>>4)*4+j (HW-verified). A/B share lane->k mapping
// (k-permutation-invariant). OOB node rows: clamped address (finite, unstored).
typedef __attribute__((ext_vector_type(8))) short bf16x8;
typedef __attribute__((ext_vector_type(4))) float f32x4;

__global__ __launch_bounds__(256)
void k_gemm1m(const unsigned short* __restrict__ hbf,
              const unsigned short* __restrict__ wt,
              unsigned short* __restrict__ fs, float* __restrict__ fd, int n){
  int tid = threadIdx.x;
  int node0 = blockIdx.x * 64;
  int mat = blockIdx.y;
  const unsigned short* W = wt + (size_t)mat*16384;
  int w = tid >> 6, lane = tid & 63;
  int rsel = lane & 15, ksel = (lane >> 4) * 8;
  int nd_a = node0 + w*16 + rsel;
  int nda = nd_a < n ? nd_a : n-1;              // clamp: garbage rows unstored
  const unsigned short* arow = hbf + (size_t)nda*128;

  bf16x8 a[4];
  #pragma unroll
  for (int ks = 0; ks < 4; ++ks)
    a[ks] = *(const bf16x8*)&arow[ks*32 + ksel];

  f32x4 acc[8];
  #pragma unroll
  for (int cf = 0; cf < 8; ++cf){ acc[cf][0]=0.f; acc[cf][1]=0.f; acc[cf][2]=0.f; acc[cf][3]=0.f; }
  #pragma unroll
  for (int cf = 0; cf < 8; ++cf){
    const unsigned short* brow = W + (size_t)(cf*16 + rsel)*128;
    #pragma unroll
    for (int ks = 0; ks < 4; ++ks){
      bf16x8 b = *(const bf16x8*)&brow[ks*32 + ksel];
      acc[cf] = __builtin_amdgcn_mfma_f32_16x16x32_bf16(a[ks], b, acc[cf], 0, 0, 0);
    }
  }
  int rq = lane >> 4;
  #pragma unroll
  for (int cf = 0; cf < 8; ++cf){
    #pragma unroll
    for (int j = 0; j < 4; ++j){
      int nd = node0 + w*16 + rq*4 + j;
      int col = cf*16 + rsel;
      if (nd < n){
        if (mat == 0) fs[(size_t)nd*128 + col] = f2bf(acc[cf][j]);
        else          fd[(size_t)nd*128 + col] = acc[cf][j];
      }
    }
  }
}

// ============ Layer 1 fused: per-node online-softmax aggregate + ELU =========
// 32 lanes per edge, 4 dims per lane, gathers are bf16x4 (8 B/lane, uint2).
// Wave = 2 edges (half-waves); 4-step butterfly in 16-lane head groups;
// defer-max rescale; validity masks; halves merged at the end.
// NOTE: `fdv_` and `out` alias (fd1 reused as h1 output): wave-private rows.
#define THR1 10.f
__global__ __launch_bounds__(256)
void k_l1_node(const unsigned* __restrict__ fs, const float* fdv_,
               const int* __restrict__ off, const unsigned short* __restrict__ csr,
               const float* __restrict__ a1, float* out, int n){
  int wid  = (int)((blockIdx.x*256u + threadIdx.x) >> 6);
  int lane = threadIdx.x & 63;
  if (wid >= n) return;
  int d  = wid;
  int hh = lane >> 5;       // which edge of the pair
  int lp = lane & 31;       // dims 4lp..4lp+3 of the edge row
  int e0 = off[d], e1 = off[d+1];
  int deg = e1 - e0;
  const uint2* fs2v = (const uint2*)fs;     // row = 32 uint2
  float4 fdv = ((const float4*)fdv_)[(size_t)d*32 + lp];
  float4 aw  = ((const float4*)a1)[lp];
  float m = FNEG_MAX, den = 0.f;
  float4 acc = make_float4(0.f, 0.f, 0.f, 0.f);

  int nt = (deg + 3) & ~3;   // multiple of 4 edges (2 iters of 2)
  for (int k = 0; k < nt; k += 4){
    int eiA = e0 + k + hh;
    int eiB = eiA + 2;
    bool vA = eiA < e1, vB = eiB < e1;
    int sA = csr[vA ? eiA : e0];
    int sB = csr[vB ? eiB : e0];
    uint2 uA = fs2v[(size_t)sA*32 + lp];
    uint2 uB = fs2v[(size_t)sB*32 + lp];
    float xA0 = bflo(uA.x), xA1 = bfhi(uA.x), xA2 = bflo(uA.y), xA3 = bfhi(uA.y);
    float xB0 = bflo(uB.x), xB1 = bfhi(uB.x), xB2 = bflo(uB.y), xB3 = bfhi(uB.y);
    float pA, pB;
    {
      float t0 = xA0 + fdv.x, t1 = xA1 + fdv.y;
      float t2 = xA2 + fdv.z, t3 = xA3 + fdv.w;
      t0 = fmaxf(t0, NEG*t0); t1 = fmaxf(t1, NEG*t1);
      t2 = fmaxf(t2, NEG*t2); t3 = fmaxf(t3, NEG*t3);
      pA = fmaf(t0, aw.x, fmaf(t1, aw.y, fmaf(t2, aw.z, t3*aw.w)));
    }
    {
      float t0 = xB0 + fdv.x, t1 = xB1 + fdv.y;
      float t2 = xB2 + fdv.z, t3 = xB3 + fdv.w;
      t0 = fmaxf(t0, NEG*t0); t1 = fmaxf(t1, NEG*t1);
      t2 = fmaxf(t2, NEG*t2); t3 = fmaxf(t3, NEG*t3);
      pB = fmaf(t0, aw.x, fmaf(t1, aw.y, fmaf(t2, aw.z, t3*aw.w)));
    }
    // 4-step butterfly within 16-lane head groups; both edges in parallel
    #pragma unroll
    for (int o = 8; o >= 1; o >>= 1){
      pA += __shfl_xor(pA, o, 64);
      pB += __shfl_xor(pB, o, 64);
    }
    pA = vA ? pA : FNEG_MAX;
    pB = vB ? pB : FNEG_MAX;
    float pmax = fmaxf(pA, pB);
    if (__any(pmax > m + THR1)){         // rare rescale
      float nm = fmaxf(m, pmax);
      float sc = __expf(m - nm);         // m==FNEG_MAX -> exp underflows to 0
      den *= sc;
      acc.x *= sc; acc.y *= sc; acc.z *= sc; acc.w *= sc;
      m = nm;
    }
    float wA = vA ? __expf(pA - m) : 0.f;
    float wB = vB ? __expf(pB - m) : 0.f;
    den += wA + wB;
    acc.x = fmaf(wA, xA0, fmaf(wB, xB0, acc.x));
    acc.y = fmaf(wA, xA1, fmaf(wB, xB1, acc.y));
    acc.z = fmaf(wA, xA2, fmaf(wB, xB2, acc.z));
    acc.w = fmaf(wA, xA3, fmaf(wB, xB3, acc.w));
  }

  // merge the two half-wave partials
  float om   = __shfl_xor(m,   32, 64);
  float oden = __shfl_xor(den, 32, 64);
  float4 oacc;
  oacc.x = __shfl_xor(acc.x, 32, 64);
  oacc.y = __shfl_xor(acc.y, 32, 64);
  oacc.z = __shfl_xor(acc.z, 32, 64);
  oacc.w = __shfl_xor(acc.w, 32, 64);
  float nm = fmaxf(m, om);
  float s1 = __expf(m - nm), s2 = __expf(om - nm);
  den = den*s1 + oden*s2;
  float4 r;
  r.x = acc.x*s1 + oacc.x*s2;
  r.y = acc.y*s1 + oacc.y*s2;
  r.z = acc.z*s1 + oacc.z*s2;
  r.w = acc.w*s1 + oacc.w*s2;
  float inv = (den > 0.f) ? 1.f/den : 0.f;
  r.x *= inv; r.y *= inv; r.z *= inv; r.w *= inv;
  r.x = r.x > 0.f ? r.x : __expf(r.x) - 1.f;   // ELU fused
  r.y = r.y > 0.f ? r.y : __expf(r.y) - 1.f;
  r.z = r.z > 0.f ? r.z : __expf(r.z) - 1.f;
  r.w = r.w > 0.f ? r.w : __expf(r.w) - 1.f;
  if (hh == 0) ((float4*)out)[(size_t)d*32 + lp] = r;
}

// ============ Layer 2 GEMM: fs2(bf16)/fd2/res = h1 @ {W2s,W2d,Wr} ===========
__global__ __launch_bounds__(256)
void k_gemm2(const float* __restrict__ h1, const float* __restrict__ Ws,
             const float* __restrict__ Wd, const float* __restrict__ Wr,
             unsigned short* __restrict__ fs2, float* __restrict__ fd2,
             float* __restrict__ res, int n){
  __shared__ float hs[16][129];
  __shared__ float w[3][128][16];
  int tid = threadIdx.x;
  for (int i = tid; i < 2048; i += 256){
    int k = i >> 4, j = i & 15;
    w[0][k][j] = Ws[i]; w[1][k][j] = Wd[i]; w[2][k][j] = Wr[i];
  }
  int node0 = blockIdx.x * 16;
  for (int i = tid; i < 2048; i += 256){
    int r = i >> 7, c = i & 127;
    int nd = node0 + r;
    hs[r][c] = (nd < n) ? h1[(size_t)nd*128 + c] : 0.f;
  }
  __syncthreads();
  int j = tid & 15, ni = tid >> 4;
  float as = 0.f, ad = 0.f, ar = 0.f;
  for (int k = 0; k < 128; ++k){
    float hv = hs[ni][k];
    as = fmaf(hv, w[0][k][j], as);
    ad = fmaf(hv, w[1][k][j], ad);
    ar = fmaf(hv, w[2][k][j], ar);
  }
  int nd = node0 + ni;
  if (nd < n){
    fs2[(size_t)nd*16 + j] = f2bf(as);
    fd2[(size_t)nd*16 + j] = ad;
    res[(size_t)nd*16 + j] = ar;
  }
}

// ============ Layer 2 fused: per-node online softmax + residual -> d_out =====
#define THR2 10.f
__global__ __launch_bounds__(256)
void k_l2_node(const unsigned short* __restrict__ fs2, const float* __restrict__ fd2,
               const float* __restrict__ resd, const int* __restrict__ off,
               const unsigned short* __restrict__ csr, const float* __restrict__ a2,
               float* __restrict__ outp, int n){
  int wid  = (int)((blockIdx.x*256u + threadIdx.x) >> 6);
  int lane = threadIdx.x & 63;
  if (wid >= n) return;
  int d = wid;
  int g = lane >> 4, j = lane & 15;
  int e0 = off[d], e1 = off[d+1];
  int deg = e1 - e0;
  float fdv = fd2[(size_t)d*16 + j];
  float aw  = a2[j];
  float m = FNEG_MAX, den = 0.f, acc = 0.f;
  int jmax = (deg + 7) >> 3;           // wave-uniform trip count
  for (int it = 0; it < jmax; ++it){
    int iA = e0 + it*8 + g;
    int iB = iA + 4;
    bool vA = iA < e1, vB = iB < e1;
    int sA = csr[vA ? iA : e0];
    int sB = csr[vB ? iB : e0];
    float xA = __uint_as_float((unsigned)fs2[(size_t)sA*16 + j] << 16);
    float xB = __uint_as_float((unsigned)fs2[(size_t)sB*16 + j] << 16);
    float tA = xA + fdv; tA = fmaxf(tA, NEG*tA);
    float tB = xB + fdv; tB = fmaxf(tB, NEG*tB);
    float pA = tA * aw, pB = tB * aw;
    #pragma unroll
    for (int o = 8; o >= 1; o >>= 1){
      pA += __shfl_xor(pA, o, 64);
      pB += __shfl_xor(pB, o, 64);
    }
    pA = vA ? pA : FNEG_MAX;
    pB = vB ? pB : FNEG_MAX;
    float pmax = fmaxf(pA, pB);
    if (__any(pmax > m + THR2)){       // rare rescale
      float nm = fmaxf(m, pmax);
      float sc = __expf(m - nm);
      den *= sc; acc *= sc;
      m = nm;
    }
    float wA = vA ? __expf(pA - m) : 0.f;
    float wB = vB ? __expf(pB - m) : 0.f;
    den += wA + wB;
    acc = fmaf(wA, xA, fmaf(wB, xB, acc));
  }
  // merge the 4 groups' (m, den, acc): butterfly xor 16 then 32
  #pragma unroll
  for (int o = 16; o <= 32; o <<= 1){
    float om   = __shfl_xor(m,   o, 64);
    float oden = __shfl_xor(den, o, 64);
    float oacc = __shfl_xor(acc, o, 64);
    float nm = fmaxf(m, om);
    float s1 = __expf(m - nm);
    float s2 = __expf(om - nm);
    den = den*s1 + oden*s2;
    acc = acc*s1 + oacc*s2;
    m = nm;
  }
  if (g == 0){
    float inv = (den > 0.f) ? 1.f/den : 0.f;
    outp[(size_t)d*16 + j] = acc*inv + resd[(size_t)d*16 + j];
  }
}

extern "C" void kernel_launch(void* const* d_in, const int* in_sizes, int n_in,
                              void* d_out, int out_size, void* d_ws, size_t ws_size,
                              hipStream_t stream) {
  const float* h    = (const float*)d_in[0];
  const int*   src  = (const int*)  d_in[1];
  const int*   dst  = (const int*)  d_in[2];
  const float* W1s  = (const float*)d_in[3];
  const float* W1d  = (const float*)d_in[4];
  const float* a1   = (const float*)d_in[5];
  const float* W2s  = (const float*)d_in[6];
  const float* W2d  = (const float*)d_in[7];
  const float* a2   = (const float*)d_in[8];
  const float* Wres = (const float*)d_in[9];
  float* out = (float*)d_out;

  const int n  = in_sizes[0] / 128;   // 50000
  const int ne = in_sizes[1];         // 1600000

  // ---- workspace layout ----
  // fs1 region is n*128 floats; fs bf16 uses first half, hbf uses second half.
  float* ws  = (float*)d_ws;
  float* fs1 = ws;                         // n*64 floats: fs bf16 (n*128 u16)
  unsigned* hbf = (unsigned*)(fs1 + (size_t)n*64);   // n*64 uints: h in bf16
  float* fd1 = fs1 + (size_t)n*128;        // n*128 (becomes h1 in k_l1_node)
  float* fs2 = fd1 + (size_t)n*128;        // n*16 region (bf16 uses n*8 floats)
  float* fd2 = fs2 + (size_t)n*16;         // n*16
  float* res = fd2 + (size_t)n*16;         // n*16
  int* deg     = (int*)(res + (size_t)n*16); // n
  int* off     = deg + n;                    // n+1
  int* pos     = off + (n+1);                // ne (per-edge intra-node slot)
  int* bsum    = pos + ne;                   // scan block sums (<= 128)
  unsigned short* csr_src = (unsigned short*)(bsum + 128);  // ne u16
  unsigned short* wt = csr_src + ((size_t)ne + 64);         // 2*16384 u16

  const int nblk = (n + SCB - 1) / SCB;

  // ---- CSR build ----
  hipMemsetAsync(deg, 0, (size_t)n*4, stream);
  k_count  <<<(ne + 255)/256, 256, 0, stream>>>(dst, deg, pos, ne);
  k_scan1  <<<nblk, SCB, 0, stream>>>(deg, off, bsum, n);
  k_scan2  <<<1, 64, 0, stream>>>(bsum, nblk);
  k_scan3  <<<nblk, SCB, 0, stream>>>(off, bsum, n, ne);
  k_scatter<<<(ne + 255)/256, 256, 0, stream>>>(src, dst, off, pos, csr_src, ne);

  // ---- layer 1 (prep once, then LDS-free MFMA gemm) ----
  int prep_items = n*32 + 2*16384;
  k_prep   <<<(prep_items + 255)/256, 256, 0, stream>>>(h, W1s, W1d, hbf, wt, n);
  k_gemm1m <<<dim3((n + 63)/64, 2), 256, 0, stream>>>(
      (const unsigned short*)hbf, wt, (unsigned short*)fs1, fd1, n);
  k_l1_node<<<(n + 3)/4, 256, 0, stream>>>((const unsigned*)fs1, fd1, off, csr_src, a1, fd1, n);

  // ---- layer 2 (writes d_out directly) ----
  k_gemm2  <<<(n + 15)/16, 256, 0, stream>>>(fd1, W2s, W2d, Wres, (unsigned short*)fs2, fd2, res, n);
  k_l2_node<<<(n + 3)/4, 256, 0, stream>>>((const unsigned short*)fs2, fd2, res, off, csr_src, a2, out, n);
}